// Round 9
// baseline (118.532 us; speedup 1.0000x reference)
//
#include <hip/hip_runtime.h>
#include <hip/hip_cooperative_groups.h>
#include <math.h>

namespace cg = cooperative_groups;

// Problem constants
#define NQ 10
#define DIM 1024          // 2^10
#define NPTS 64
#define DFEAT 10
#define NLAYERS 5
#define SREGS 4           // amps per thread (DIM / 256)
#define NPAIR 2080        // 64*65/2 upper-triangle pairs
#define NWAVE 256         // 64 blocks * 4 waves

#define IS2 0.70710678118654752440f

// ws layout: psi (64*1024 float2 = 512 KB) | partials (2*NPTS floats)
#define PART_OFF ((size_t)NPTS * DIM * sizeof(float2))

// ---------------------------------------------------------------------------
// ONE cooperative kernel: state -> grid.sync -> gram -> grid.sync -> reduce.
// R8 lesson: two different state micro-structures gave identical totals ->
// the 3-kernel pipeline's fixed costs (3 cold starts after the 268 MB cache
// sweep + 2 launch gaps) dominate the non-fill time. Fuse everything.
//
// Phase 1 (state): amp idx = (r<<8)|(wv<<6)|lane. Bits 0..5 lane (shfl_xor,
// batched 8-deep, mc coeffs preloaded to registers -> 6 unrolled stages,
// ~2 KB code, far under the R4 I-fetch cliff), bits 6..7 wave (LDS exchange,
// single barrier via double-buffer), bits 8..9 register.
// Verified algebra (absmax==0, R4-R8): fused M = RY(t)*RZ(x)*H with
// x angle x[9-q] every layer; layer 0 on |0> = product state; layer 5 ring
// + RY are data-independent outer unitaries -> cancel in |<psi_j|psi_i>|^2.
//   cx=cos(x/2), sx=sin(x/2), c=cos(t/2), s=sin(t/2), p=(c+s)/sqrt2,
//   q=(c-s)/sqrt2: m00=(q*cx,-p*sx) m01=(p*cx,-q*sx) m10=conj(m01)
//   m11=-conj(m00)  (store m00,m01 as float4).
//
// Phase 2 (gram): wave g handles pairs w = g, g+256, ... over the upper
// triangle (closed-form index, verified R7/R8); slk/skk accumulate in
// registers; block combines 4 waves in LDS -> 2 floats to partials.
// No atomics (R6 lesson: single-address RMW chains serialize ~100cyc each).
//
// Phase 3: block 0 only. wave0 reduces slk partials, wave1 skk, wave2 sum l^2.
// ---------------------------------------------------------------------------

#define SHFL_STAGE(Q, M)                                                      \
    {                                                                         \
        const int   b   = (lane >> (Q)) & 1;                                  \
        const float msr = b ? -(M).x : (M).x;   /* m11r / m00r */             \
        const float msi = (M).y;                /* m11i == m00i */            \
        const float mpr = (M).z;                /* m10r == m01r */            \
        const float mpi = b ? -(M).w : (M).w;   /* m10i / m01i */             \
        float pr[SREGS], pi[SREGS];                                           \
        _Pragma("unroll")                                                     \
        for (int r = 0; r < SREGS; ++r) {                                     \
            pr[r] = __shfl_xor(re[r], 1 << (Q), 64);                          \
            pi[r] = __shfl_xor(im[r], 1 << (Q), 64);                          \
        }                                                                     \
        _Pragma("unroll")                                                     \
        for (int r = 0; r < SREGS; ++r) {                                     \
            const float nr = msr * re[r] - msi * im[r] + mpr * pr[r] - mpi * pi[r]; \
            const float ni = msr * im[r] + msi * re[r] + mpr * pi[r] + mpi * pr[r]; \
            re[r] = nr; im[r] = ni;                                           \
        }                                                                     \
    }

__global__ __launch_bounds__(256) void fused_kernel(
    const float* __restrict__ data,     // (64,10)
    const float* __restrict__ labels,   // (64,)
    const float* __restrict__ params,   // (5,2,10)
    float2* __restrict__ psi,           // (64,1024) ws
    float* __restrict__ partials,       // (2*NPTS,) ws
    float* __restrict__ out)            // (1,)
{
    cg::grid_group grid = cg::this_grid();
    const int blk  = blockIdx.x;        // 0..63 = data point
    const int tid  = threadIdx.x;
    const int lane = tid & 63;
    const int wv   = tid >> 6;

    __shared__ float4 mc[NLAYERS][NQ];     // (m00r, m00i, m01r, m01i)
    __shared__ float2 xb[2][16][64];       // double-buffered exchange (16 KB)
    __shared__ float  sm[4][4];

    // ======================= phase 1: state =======================
    if (tid < NLAYERS * NQ) {
        const int L = tid / NQ, q = tid - L * NQ;
        const float xh = 0.5f * data[blk * DFEAT + (9 - q)];
        const float cx = __cosf(xh), sx = __sinf(xh);
        float c = 1.f, s = 0.f;
        if (L != NLAYERS - 1) {
            const float th = 0.5f * params[L * 2 * NQ + q];
            c = __cosf(th); s = __sinf(th);
        }
        const float p = (c + s) * IS2, qm = (c - s) * IS2;
        mc[L][q] = make_float4(qm * cx, -p * sx, p * cx, -qm * sx);
    }
    __syncthreads();

    float re[SREGS], im[SREGS];

    // layer 0: product state (no exchanges)
    {
        float Pr = 1.f, Pi = 0.f;
#pragma unroll 1
        for (int q = 0; q < 8; ++q) {
            const float4 m = mc[0][q];
            const int b = (q < 6) ? ((lane >> q) & 1) : ((wv >> (q - 6)) & 1);
            const float fr = b ? m.z : m.x;          // u1=m10, u0=m00
            const float fi = b ? -m.w : m.y;
            const float nr = Pr * fr - Pi * fi;
            const float ni = Pr * fi + Pi * fr;
            Pr = nr; Pi = ni;
        }
        const float4 m8 = mc[0][8], m9 = mc[0][9];
        const float u8r[2] = {m8.x, m8.z}, u8i[2] = {m8.y, -m8.w};
        const float u9r[2] = {m9.x, m9.z}, u9i[2] = {m9.y, -m9.w};
#pragma unroll
        for (int r = 0; r < SREGS; ++r) {
            const int b8 = r & 1, b9 = (r >> 1) & 1;
            const float vr = u8r[b8] * u9r[b9] - u8i[b8] * u9i[b9];
            const float vi = u8r[b8] * u9i[b9] + u8i[b8] * u9r[b9];
            re[r] = Pr * vr - Pi * vi;
            im[r] = Pr * vi + Pi * vr;
        }
    }

    int sp = 0;   // exchange-buffer parity

#pragma unroll 1
    for (int L = 0; L < NLAYERS; ++L) {
        if (L > 0) {
            // qubits 0..5: preload coeffs (6 batched ds_read_b128), unrolled
            const float4 m0 = mc[L][0], m1 = mc[L][1], m2 = mc[L][2];
            const float4 m3 = mc[L][3], m4 = mc[L][4], m5 = mc[L][5];
            SHFL_STAGE(0, m0) SHFL_STAGE(1, m1) SHFL_STAGE(2, m2)
            SHFL_STAGE(3, m3) SHFL_STAGE(4, m4) SHFL_STAGE(5, m5)

            // qubits 6..7: cross-wave via LDS, ONE barrier per stage
#pragma unroll 1
            for (int q = 6; q < 8; ++q) {
                const float4 m = mc[L][q];
                const int   b = (wv >> (q - 6)) & 1;
                const float msr = b ? -m.x : m.x;
                const float msi = m.y;
                const float mpr = m.z;
                const float mpi = b ? -m.w : m.w;
#pragma unroll
                for (int r = 0; r < SREGS; ++r)
                    xb[sp][(wv << 2) | r][lane] = make_float2(re[r], im[r]);
                __syncthreads();
                const int pw = wv ^ (1 << (q - 6));
#pragma unroll
                for (int r = 0; r < SREGS; ++r) {
                    const float2 p2 = xb[sp][(pw << 2) | r][lane];
                    const float nr = msr * re[r] - msi * im[r] + mpr * p2.x - mpi * p2.y;
                    const float ni = msr * im[r] + msi * re[r] + mpr * p2.y + mpi * p2.x;
                    re[r] = nr; im[r] = ni;
                }
                sp ^= 1;   // next stage uses other buffer (dbuf safety: R8)
            }

            // qubits 8..9: in-register butterfly
#pragma unroll
            for (int q = 8; q < 10; ++q) {
                const int mask = 1 << (q - 8);
                const float4 m = mc[L][q];
                const float m00r = m.x, m00i = m.y, m01r = m.z, m01i = m.w;
                const float m10r = m.z, m10i = -m.w, m11r = -m.x, m11i = m.y;
#pragma unroll
                for (int r = 0; r < SREGS; ++r) {
                    if (!(r & mask)) {
                        const int r1 = r | mask;
                        const float a0r = re[r],  a0i = im[r];
                        const float a1r = re[r1], a1i = im[r1];
                        re[r]  = m00r * a0r - m00i * a0i + m01r * a1r - m01i * a1i;
                        im[r]  = m00r * a0i + m00i * a0r + m01r * a1i + m01i * a1r;
                        re[r1] = m10r * a0r - m10i * a0i + m11r * a1r - m11i * a1i;
                        im[r1] = m10r * a0i + m10i * a0r + m11r * a1i + m11i * a1r;
                    }
                }
            }
        }

        // crz ring diagonal (skip layer 5: cancels)
        if (L < NLAYERS - 1) {
            const float* rg = params + L * 2 * NQ + NQ;
            float ph[SREGS] = {0.f, 0.f, 0.f, 0.f};
#pragma unroll 1
            for (int n = 0; n < NQ; ++n) {
                const int   nn = (n == 9) ? 0 : (n + 1);
                const float g  = rg[n];     // wave-uniform -> s_load
#pragma unroll
                for (int r = 0; r < SREGS; ++r) {
                    const int idx = (r << 8) | (wv << 6) | lane;
                    const float t = (((idx >> nn) & 1) ? 0.5f : -0.5f) * g;
                    ph[r] += ((idx >> n) & 1) ? t : 0.f;
                }
            }
#pragma unroll
            for (int r = 0; r < SREGS; ++r) {
                const float s = __sinf(ph[r]), c = __cosf(ph[r]);
                const float nr = re[r] * c - im[r] * s;
                const float ni = re[r] * s + im[r] * c;
                re[r] = nr; im[r] = ni;
            }
        }
    }

    // write psi_blk (coalesced float2)
    {
        float2* o = psi + blk * DIM;
#pragma unroll
        for (int r = 0; r < SREGS; ++r)
            o[(r << 8) | (wv << 6) | lane] = make_float2(re[r], im[r]);
    }
    __threadfence();
    grid.sync();

    // ======================= phase 2: gram =======================
    {
        const float4* psi4 = (const float4*)psi;
        const int gwave = blk * 4 + wv;       // 0..255
        float wslk = 0.f, wskk = 0.f;

#pragma unroll 1
        for (int w = gwave; w < NPAIR; w += NWAVE) {
            // triangle index (verified R7/R8)
            int i = (int)((129.0f - sqrtf(16641.0f - 8.0f * (float)w)) * 0.5f);
            int Ci = 64 * i - ((i * (i - 1)) >> 1);
            while (w < Ci)            { --i; Ci = 64 * i - ((i * (i - 1)) >> 1); }
            while (w >= Ci + 64 - i)  { Ci += 64 - i; ++i; }
            const int j = i + (w - Ci);

            const float4* a = psi4 + i * (DIM / 2);
            const float4* b = psi4 + j * (DIM / 2);
            float zr = 0.f, zi = 0.f;   // <psi_j|psi_i> = sum conj(b)*a
#pragma unroll
            for (int r = 0; r < 8; ++r) {
                const int k = (r << 6) | lane;
                const float4 av = a[k], bv = b[k];
                zr += bv.x * av.x + bv.y * av.y + bv.z * av.z + bv.w * av.w;
                zi += bv.x * av.y - bv.y * av.x + bv.z * av.w - bv.w * av.z;
            }
#pragma unroll
            for (int off = 32; off; off >>= 1) {
                zr += __shfl_xor(zr, off, 64);
                zi += __shfl_xor(zi, off, 64);
            }
            const float k   = zr * zr + zi * zi;
            const float wgt = (i == j) ? 1.f : 2.f;
            wslk += wgt * labels[i] * labels[j] * k;
            wskk += wgt * k * k;
        }

        if (lane == 0) { sm[0][wv] = wslk; sm[1][wv] = wskk; }
        __syncthreads();
        if (tid == 0) {
            partials[2 * blk]     = sm[0][0] + sm[0][1] + sm[0][2] + sm[0][3];
            partials[2 * blk + 1] = sm[1][0] + sm[1][1] + sm[1][2] + sm[1][3];
        }
    }
    __threadfence();
    grid.sync();

    // ======================= phase 3: final KTA (block 0) =======================
    if (blk == 0) {
        float v = 0.f;
        if (wv == 0)      v = partials[2 * lane];           // slk parts
        else if (wv == 1) v = partials[2 * lane + 1];       // skk parts
        else if (wv == 2) { const float l = labels[lane]; v = l * l; }
#pragma unroll
        for (int off = 32; off; off >>= 1) v += __shfl_xor(v, off, 64);
        if (lane == 0) sm[3][wv] = v;
        __syncthreads();
        if (tid == 0) {
            const float slk = sm[3][0];
            const float skk = sm[3][1];
            const float sl2 = sm[3][2];
            out[0] = slk / sqrtf(skk * (sl2 * sl2));
        }
    }
}

extern "C" void kernel_launch(void* const* d_in, const int* in_sizes, int n_in,
                              void* d_out, int out_size, void* d_ws, size_t ws_size,
                              hipStream_t stream) {
    const float* data   = (const float*)d_in[0];  // (64,10)
    const float* labels = (const float*)d_in[1];  // (64,)
    const float* params = (const float*)d_in[2];  // (5,2,10)
    float* out = (float*)d_out;

    float2* psi      = (float2*)d_ws;
    float*  partials = (float*)((char*)d_ws + PART_OFF);

    void* args[] = { (void*)&data, (void*)&labels, (void*)&params,
                     (void*)&psi, (void*)&partials, (void*)&out };
    hipLaunchCooperativeKernel((void*)fused_kernel, dim3(NPTS), dim3(256),
                               args, 0, stream);
}

// Round 10
// 84.199 us; speedup vs baseline: 1.4078x; 1.4078x over previous
//
#include <hip/hip_runtime.h>
#include <math.h>

// Problem constants
#define NQ 10
#define DIM 1024          // 2^10
#define NPTS 64
#define DFEAT 10
#define NLAYERS 5
#define NPAIR 2080        // 64*65/2 upper-triangle pairs
#define NBUCKET 16        // bucketed accumulators (4-deep chains at 64 blocks)

#define IS2 0.70710678118654752440f

// ws layout: psi (64*1024 float2 = 512 KB) | acc: slk[16] skk[16] ticket
#define ACC_OFF ((size_t)NPTS * DIM * sizeof(float2))

// ---------------------------------------------------------------------------
// Kernel 1: psi_i = U(x_i)|0>. 64 blocks x 1024 threads (16 waves), one amp
// per thread: idx = tid. Bits 0..5 cross-lane (shfl_xor), bits 6..9
// cross-wave (LDS exchange, ONE barrier per stage via double-buffering).
//
// Lessons: R4 keep loops ROLLED (unrolled = I-fetch bound); R6 no deep
// single-address atomic chains; R7 16-wave shape beats 4-wave; R8 dbuf
// halves barriers safely (re-write of buf p is ordered after the next
// stage's barrier, which every read of old buf p precedes); R9 cooperative
// grid.sync costs ~10-15us each -- stay with separate kernels.
//
// Verified algebra (absmax==0, R4-R9): fused 1q gate M = RY(t)*RZ(x)*H,
// x angle = x[9-q] every layer (all starts % 10 == 0). cx=cos(x/2),
// sx=sin(x/2), c=cos(t/2), s=sin(t/2), p=(c+s)/sqrt2, q=(c-s)/sqrt2:
//   m00=(q*cx,-p*sx) m01=(p*cx,-q*sx) m10=conj(m01) m11=-conj(m00)
// layer 0 on |0> -> product state (no exchanges); layer 5 ring + RY are
// data-independent outer unitaries -> cancel in |<psi_j|psi_i>|^2.
// Block 0 also zeroes the gram accumulators (ws re-poisoned every call).
// ---------------------------------------------------------------------------
__global__ __launch_bounds__(1024) void state_kernel(
    const float* __restrict__ data,     // (64,10)
    const float* __restrict__ params,   // (5,2,10)
    float2* __restrict__ psi,           // (64,1024)
    float* __restrict__ acc)            // slk[16] skk[16] ticket
{
    const int i    = blockIdx.x;
    const int tid  = threadIdx.x;
    const int lane = tid & 63;

    if (i == 0 && tid < 2 * NBUCKET + 1) acc[tid] = 0.f;

    __shared__ float4 mc[NLAYERS][NQ];   // (m00r, m00i, m01r, m01i)
    __shared__ float2 xb[2][DIM];        // double-buffered exchange (16 KB)

    // ---- precompute fused gate coefficients (50 threads, once) ----
    if (tid < NLAYERS * NQ) {
        const int L = tid / NQ, q = tid - L * NQ;
        const float xh = 0.5f * data[i * DFEAT + (9 - q)];
        const float cx = __cosf(xh), sx = __sinf(xh);
        float c = 1.f, s = 0.f;
        if (L != NLAYERS - 1) {
            const float th = 0.5f * params[L * 2 * NQ + q];
            c = __cosf(th); s = __sinf(th);
        }
        const float p = (c + s) * IS2, qm = (c - s) * IS2;
        mc[L][q] = make_float4(qm * cx, -p * sx, p * cx, -qm * sx);
    }
    __syncthreads();

    // ---- layer 0: product state ----
    float re, im;
    {
        float Pr = 1.f, Pi = 0.f;
#pragma unroll 1
        for (int q = 0; q < NQ; ++q) {
            const float4 m = mc[0][q];
            const int b = (tid >> q) & 1;
            const float fr = b ? m.z : m.x;      // u1 = m10, u0 = m00
            const float fi = b ? -m.w : m.y;
            const float nr = Pr * fr - Pi * fi;
            const float ni = Pr * fi + Pi * fr;
            Pr = nr; Pi = ni;
        }
        re = Pr; im = Pi;
    }

    int sp = 0;   // exchange-buffer parity

#pragma unroll 1
    for (int L = 0; L < NLAYERS; ++L) {
        if (L > 0) {
            // ---- qubits 0..5: cross-lane butterfly (rolled) ----
#pragma unroll 1
            for (int q = 0; q < 6; ++q) {
                const float4 m = mc[L][q];
                const int   b = (lane >> q) & 1;
                const float msr = b ? -m.x : m.x;   // m11r / m00r
                const float msi = m.y;              // m11i == m00i
                const float mpr = m.z;              // m10r == m01r
                const float mpi = b ? -m.w : m.w;   // m10i / m01i
                const float pr = __shfl_xor(re, 1 << q, 64);
                const float pi = __shfl_xor(im, 1 << q, 64);
                const float nr = msr * re - msi * im + mpr * pr - mpi * pi;
                const float ni = msr * im + msi * re + mpr * pi + mpi * pr;
                re = nr; im = ni;
            }
            // ---- qubits 6..9: cross-wave via LDS, ONE barrier per stage ----
#pragma unroll 1
            for (int q = 6; q < NQ; ++q) {
                const float4 m = mc[L][q];
                const int   b = (tid >> q) & 1;
                const float msr = b ? -m.x : m.x;
                const float msi = m.y;
                const float mpr = m.z;
                const float mpi = b ? -m.w : m.w;
                xb[sp][tid] = make_float2(re, im);
                __syncthreads();
                const float2 p2 = xb[sp][tid ^ (1 << q)];
                const float nr = msr * re - msi * im + mpr * p2.x - mpi * p2.y;
                const float ni = msr * im + msi * re + mpr * p2.y + mpi * p2.x;
                re = nr; im = ni;
                sp ^= 1;   // next stage uses the other buffer — no 2nd barrier
            }
        }

        // ---- crz ring diagonal (skip layer 5: cancels) ----
        if (L < NLAYERS - 1) {
            const float* rg = params + L * 2 * NQ + NQ;
            float ph = 0.f;
#pragma unroll 1
            for (int n = 0; n < NQ; ++n) {
                const int   nn = (n == 9) ? 0 : (n + 1);
                const float g  = rg[n];     // wave-uniform -> s_load
                const float t  = (((tid >> nn) & 1) ? 0.5f : -0.5f) * g;
                ph += ((tid >> n) & 1) ? t : 0.f;
            }
            const float s = __sinf(ph), c = __cosf(ph);
            const float nr = re * c - im * s;
            const float ni = re * s + im * c;
            re = nr; im = ni;
        }
    }

    psi[i * DIM + tid] = make_float2(re, im);
}

// ---------------------------------------------------------------------------
// Kernel 2: gram + final KTA, 64 blocks x 256 threads.
// Wave g = blk*4+wv accumulates pairs w = g, g+256, ... over the upper
// triangle in REGISTERS (closed-form decode, verified R7-R9); off-diagonals
// weighted 2. Block partials -> 16-way bucketed device atomics (4-deep
// chains). 64-deep ticket (cheap, vs R6's 1024) elects the last block;
// its wave 0 reduces buckets + labels in parallel and writes
//   out = slk / sqrt(skk * (sum l^2)^2).
// ---------------------------------------------------------------------------
__global__ __launch_bounds__(256) void gram_kernel(
    const float4* __restrict__ psi4,    // (64, 512) float4 view of psi
    const float* __restrict__ labels,   // (64,)
    float* __restrict__ acc,            // slk[16] skk[16] ticket
    float* __restrict__ out)            // (1,)
{
    __shared__ float sm[2][4];
    __shared__ int   islast;
    const int blk  = blockIdx.x;
    const int tid  = threadIdx.x;
    const int wv   = tid >> 6;
    const int lane = tid & 63;
    const int g    = blk * 4 + wv;      // 0..255

    float wslk = 0.f, wskk = 0.f;
#pragma unroll 1
    for (int w = g; w < NPAIR; w += 256) {
        int i = (int)((129.0f - sqrtf(16641.0f - 8.0f * (float)w)) * 0.5f);
        int Ci = 64 * i - ((i * (i - 1)) >> 1);
        while (w < Ci)            { --i; Ci = 64 * i - ((i * (i - 1)) >> 1); }
        while (w >= Ci + 64 - i)  { Ci += 64 - i; ++i; }
        const int j = i + (w - Ci);

        const float4* a = psi4 + i * (DIM / 2);
        const float4* b = psi4 + j * (DIM / 2);
        float zr = 0.f, zi = 0.f;       // <psi_j|psi_i> = sum conj(b)*a
#pragma unroll
        for (int r = 0; r < 8; ++r) {
            const int k = (r << 6) | lane;
            const float4 av = a[k], bv = b[k];
            zr += bv.x * av.x + bv.y * av.y + bv.z * av.z + bv.w * av.w;
            zi += bv.x * av.y - bv.y * av.x + bv.z * av.w - bv.w * av.z;
        }
#pragma unroll
        for (int off = 32; off; off >>= 1) {
            zr += __shfl_xor(zr, off, 64);
            zi += __shfl_xor(zi, off, 64);
        }
        const float k   = zr * zr + zi * zi;
        const float wgt = (i == j) ? 1.f : 2.f;
        wslk += wgt * labels[i] * labels[j] * k;
        wskk += wgt * k * k;
    }

    if (lane == 0) { sm[0][wv] = wslk; sm[1][wv] = wskk; }
    __syncthreads();

    if (tid == 0) {
        const float bs = sm[0][0] + sm[0][1] + sm[0][2] + sm[0][3];
        const float bk = sm[1][0] + sm[1][1] + sm[1][2] + sm[1][3];
        const int bkt = blk & (NBUCKET - 1);
        atomicAdd(&acc[bkt], bs);
        atomicAdd(&acc[NBUCKET + bkt], bk);
        __threadfence();
        unsigned* ticket = (unsigned*)(acc + 2 * NBUCKET);
        islast = (atomicAdd(ticket, 1u) == (unsigned)(gridDim.x - 1)) ? 1 : 0;
    }
    __syncthreads();

    if (islast && wv == 0) {
        // parallel final reduce: lanes 0..15 read buckets, all 64 read labels
        float va = (lane < NBUCKET) ? atomicAdd(&acc[lane], 0.f) : 0.f;
        float vb = (lane < NBUCKET) ? atomicAdd(&acc[NBUCKET + lane], 0.f) : 0.f;
        const float l = labels[lane];
        float vl = l * l;
#pragma unroll
        for (int off = 32; off; off >>= 1) {
            va += __shfl_xor(va, off, 64);
            vb += __shfl_xor(vb, off, 64);
            vl += __shfl_xor(vl, off, 64);
        }
        if (lane == 0) out[0] = va / sqrtf(vb * (vl * vl));
    }
}

extern "C" void kernel_launch(void* const* d_in, const int* in_sizes, int n_in,
                              void* d_out, int out_size, void* d_ws, size_t ws_size,
                              hipStream_t stream) {
    const float* data   = (const float*)d_in[0];  // (64,10)
    const float* labels = (const float*)d_in[1];  // (64,)
    const float* params = (const float*)d_in[2];  // (5,2,10)
    float* out = (float*)d_out;

    float2* psi = (float2*)d_ws;
    float*  acc = (float*)((char*)d_ws + ACC_OFF);

    state_kernel<<<NPTS, 1024, 0, stream>>>(data, params, psi, acc);
    gram_kernel <<<NPTS,  256, 0, stream>>>((const float4*)psi, labels, acc, out);
}

// Round 11
// 74.133 us; speedup vs baseline: 1.5989x; 1.1358x over previous
//
#include <hip/hip_runtime.h>
#include <math.h>

// Problem constants
#define NQ 10
#define DIM 1024          // 2^10
#define NPTS 64
#define DFEAT 10
#define NLAYERS 5
#define NPAIR 2080        // 64*65/2 upper-triangle pairs
#define GBLK  (NPAIR / 4) // 520 gram blocks, 4 waves each

#define IS2 0.70710678118654752440f

// ws layout: psi (64*1024 float2 = 512 KB) | partials (GBLK float2)
#define PART_OFF ((size_t)NPTS * DIM * sizeof(float2))

// ---------------------------------------------------------------------------
// Kernel 1: psi_i = U(x_i)|0>. 64 blocks x 1024 threads (16 waves), one amp
// per thread (idx = tid). Bits 0..5 cross-lane (shfl_xor), bits 6..9
// cross-wave (LDS exchange, ONE barrier per stage via double-buffering).
//
// Session lessons baked in:
//  R2  batch/overlap DS ops;        R4  keep loops ROLLED (I-fetch cliff)
//  R6  no deep single-address atomic chains
//  R7  16-wave 1024-thr state + 520-block gram + tiny reduce = best (73.9us)
//  R8  dbuf halves barriers safely (buf-p rewrite is ordered after the next
//      stage's barrier, which every read of old buf p precedes)
//  R9  grid.sync ~10-15us each -> never cooperative here
//  R10 gram must stay 1 pair/wave at high occupancy (serial pair loops at
//      1 wave/CU and tickets both lose more than a launch costs)
//
// Verified algebra (absmax==0, R4-R10): fused 1q gate M = RY(t)*RZ(x)*H,
// x angle = x[9-q] every layer (all starts % 10 == 0). cx=cos(x/2),
// sx=sin(x/2), c=cos(t/2), s=sin(t/2), p=(c+s)/sqrt2, q=(c-s)/sqrt2:
//   m00=(q*cx,-p*sx) m01=(p*cx,-q*sx) m10=conj(m01) m11=-conj(m00)
// layer 0 on |0> -> product state (no exchanges); layer 5 ring + RY are
// data-independent outer unitaries -> cancel in |<psi_j|psi_i>|^2.
// Ring coefficient pattern (0/+-0.5 per tid,n) is layer-invariant ->
// precomputed once in registers; per-layer ring = 10 FMAs + sincos.
// ---------------------------------------------------------------------------
__global__ __launch_bounds__(1024) void state_kernel(
    const float* __restrict__ data,     // (64,10)
    const float* __restrict__ params,   // (5,2,10)
    float2* __restrict__ psi)           // (64,1024)
{
    const int i    = blockIdx.x;
    const int tid  = threadIdx.x;
    const int lane = tid & 63;

    __shared__ float4 mc[NLAYERS][NQ];   // (m00r, m00i, m01r, m01i)
    __shared__ float2 xb[2][DIM];        // double-buffered exchange (16 KB)

    // ---- precompute fused gate coefficients (50 threads, once) ----
    if (tid < NLAYERS * NQ) {
        const int L = tid / NQ, q = tid - L * NQ;
        const float xh = 0.5f * data[i * DFEAT + (9 - q)];
        const float cx = __cosf(xh), sx = __sinf(xh);
        float c = 1.f, s = 0.f;
        if (L != NLAYERS - 1) {
            const float th = 0.5f * params[L * 2 * NQ + q];
            c = __cosf(th); s = __sinf(th);
        }
        const float p = (c + s) * IS2, qm = (c - s) * IS2;
        mc[L][q] = make_float4(qm * cx, -p * sx, p * cx, -qm * sx);
    }

    // ---- ring coefficient pattern (layer-invariant, per tid) ----
    float rc[NQ];
#pragma unroll 1
    for (int n = 0; n < NQ; ++n) {
        const int nn = (n == 9) ? 0 : (n + 1);
        const float t = ((tid >> nn) & 1) ? 0.5f : -0.5f;
        rc[n] = ((tid >> n) & 1) ? t : 0.f;
    }
    __syncthreads();

    // ---- layer 0: product state ----
    float re, im;
    {
        float Pr = 1.f, Pi = 0.f;
#pragma unroll 1
        for (int q = 0; q < NQ; ++q) {
            const float4 m = mc[0][q];
            const int b = (tid >> q) & 1;
            const float fr = b ? m.z : m.x;      // u1 = m10, u0 = m00
            const float fi = b ? -m.w : m.y;
            const float nr = Pr * fr - Pi * fi;
            const float ni = Pr * fi + Pi * fr;
            Pr = nr; Pi = ni;
        }
        re = Pr; im = Pi;
    }

    int sp = 0;   // exchange-buffer parity

#pragma unroll 1
    for (int L = 0; L < NLAYERS; ++L) {
        if (L > 0) {
            // ---- qubits 0..5: cross-lane butterfly (rolled) ----
#pragma unroll 1
            for (int q = 0; q < 6; ++q) {
                const float4 m = mc[L][q];
                const int   b = (lane >> q) & 1;
                const float msr = b ? -m.x : m.x;   // m11r / m00r
                const float msi = m.y;              // m11i == m00i
                const float mpr = m.z;              // m10r == m01r
                const float mpi = b ? -m.w : m.w;   // m10i / m01i
                const float pr = __shfl_xor(re, 1 << q, 64);
                const float pi = __shfl_xor(im, 1 << q, 64);
                const float nr = msr * re - msi * im + mpr * pr - mpi * pi;
                const float ni = msr * im + msi * re + mpr * pi + mpi * pr;
                re = nr; im = ni;
            }
            // ---- qubits 6..9: cross-wave via LDS, ONE barrier per stage ----
#pragma unroll 1
            for (int q = 6; q < NQ; ++q) {
                const float4 m = mc[L][q];
                const int   b = (tid >> q) & 1;
                const float msr = b ? -m.x : m.x;
                const float msi = m.y;
                const float mpr = m.z;
                const float mpi = b ? -m.w : m.w;
                xb[sp][tid] = make_float2(re, im);
                __syncthreads();
                const float2 p2 = xb[sp][tid ^ (1 << q)];
                const float nr = msr * re - msi * im + mpr * p2.x - mpi * p2.y;
                const float ni = msr * im + msi * re + mpr * p2.y + mpi * p2.x;
                re = nr; im = ni;
                sp ^= 1;   // next stage uses the other buffer — no 2nd barrier
            }
        }

        // ---- crz ring diagonal (skip layer 5: cancels) ----
        if (L < NLAYERS - 1) {
            const float* rg = params + L * 2 * NQ + NQ;
            float ph = 0.f;
#pragma unroll 1
            for (int n = 0; n < NQ; ++n)
                ph += rc[n] * rg[n];        // rg wave-uniform -> s_load
            const float s = __sinf(ph), c = __cosf(ph);
            const float nr = re * c - im * s;
            const float ni = re * s + im * c;
            re = nr; im = ni;
        }
    }

    psi[i * DIM + tid] = make_float2(re, im);
}

// ---------------------------------------------------------------------------
// Kernel 2: gram partials over the UPPER TRIANGLE (R7-proven). 520 blocks x
// 4 waves, ONE pair per wave (8 waves/CU). Closed-form triangle decode.
// Off-diagonals weighted 2. Partials written unconditionally as float2.
// ---------------------------------------------------------------------------
__global__ __launch_bounds__(256) void gram_kernel(
    const float4* __restrict__ psi4,    // (64, 512) float4 view of psi
    const float* __restrict__ labels,   // (64,)
    float2* __restrict__ partials)      // (GBLK,) = (slk_part, skk_part)
{
    __shared__ float sm[2][4];
    const int wave = threadIdx.x >> 6;
    const int lane = threadIdx.x & 63;
    const int w    = blockIdx.x * 4 + wave;   // 0..2079

    int i = (int)((129.0f - sqrtf(16641.0f - 8.0f * (float)w)) * 0.5f);
    int Ci = 64 * i - ((i * (i - 1)) >> 1);
    while (w < Ci)            { --i; Ci = 64 * i - ((i * (i - 1)) >> 1); }
    while (w >= Ci + 64 - i)  { Ci += 64 - i; ++i; }
    const int j = i + (w - Ci);

    const float4* a = psi4 + i * (DIM / 2);
    const float4* b = psi4 + j * (DIM / 2);

    float zr = 0.f, zi = 0.f;   // <psi_j|psi_i> = sum conj(b)*a
#pragma unroll
    for (int r = 0; r < 8; ++r) {
        const int k = (r << 6) | lane;
        const float4 av = a[k], bv = b[k];
        zr += bv.x * av.x + bv.y * av.y + bv.z * av.z + bv.w * av.w;
        zi += bv.x * av.y - bv.y * av.x + bv.z * av.w - bv.w * av.z;
    }
#pragma unroll
    for (int off = 32; off; off >>= 1) {
        zr += __shfl_xor(zr, off, 64);
        zi += __shfl_xor(zi, off, 64);
    }

    if (lane == 0) {
        const float k = zr * zr + zi * zi;
        const float wgt = (i == j) ? 1.f : 2.f;
        sm[0][wave] = wgt * labels[i] * labels[j] * k;
        sm[1][wave] = wgt * k * k;
    }
    __syncthreads();
    if (threadIdx.x == 0)
        partials[blockIdx.x] = make_float2(sm[0][0] + sm[0][1] + sm[0][2] + sm[0][3],
                                           sm[1][0] + sm[1][1] + sm[1][2] + sm[1][3]);
}

// ---------------------------------------------------------------------------
// Kernel 3: final KTA (R7-proven). One 256-thread block, float2 partials.
// out = slk / sqrt(skk * (sum l^2)^2)
// ---------------------------------------------------------------------------
__global__ __launch_bounds__(256) void reduce_kernel(
    const float2* __restrict__ partials,
    const float* __restrict__ labels,
    float* __restrict__ out)
{
    __shared__ float sm[3][4];
    const int tid  = threadIdx.x;
    const int lane = tid & 63;
    const int wave = tid >> 6;

    float slk = 0.f, skk = 0.f, sl2 = 0.f;
    for (int p = tid; p < GBLK; p += 256) {
        const float2 v = partials[p];
        slk += v.x;
        skk += v.y;
    }
    if (tid < NPTS) { const float l = labels[tid]; sl2 = l * l; }

#pragma unroll
    for (int off = 32; off; off >>= 1) {
        slk += __shfl_xor(slk, off, 64);
        skk += __shfl_xor(skk, off, 64);
        sl2 += __shfl_xor(sl2, off, 64);
    }
    if (lane == 0) { sm[0][wave] = slk; sm[1][wave] = skk; sm[2][wave] = sl2; }
    __syncthreads();
    if (tid == 0) {
        const float a = sm[0][0] + sm[0][1] + sm[0][2] + sm[0][3];
        const float b = sm[1][0] + sm[1][1] + sm[1][2] + sm[1][3];
        const float c = sm[2][0] + sm[2][1] + sm[2][2] + sm[2][3];
        out[0] = a / sqrtf(b * (c * c));
    }
}

extern "C" void kernel_launch(void* const* d_in, const int* in_sizes, int n_in,
                              void* d_out, int out_size, void* d_ws, size_t ws_size,
                              hipStream_t stream) {
    const float* data   = (const float*)d_in[0];  // (64,10)
    const float* labels = (const float*)d_in[1];  // (64,)
    const float* params = (const float*)d_in[2];  // (5,2,10)
    float* out = (float*)d_out;

    float2* psi      = (float2*)d_ws;
    float2* partials = (float2*)((char*)d_ws + PART_OFF);

    state_kernel <<<NPTS, 1024, 0, stream>>>(data, params, psi);
    gram_kernel  <<<GBLK,  256, 0, stream>>>((const float4*)psi, labels, partials);
    reduce_kernel<<<1,     256, 0, stream>>>(partials, labels, out);
}